// Round 1
// baseline (426.457 us; speedup 1.0000x reference)
//
#include <hip/hip_runtime.h>

#define NN 4096
#define DD 64
#define NB 7
#define EPSV 1e-8f
#define BM 64
#define BK 64
#define LDK 72   // 64 + 8 bf16 pad (16B) -> conflict-free-ish ds_read_b128

typedef __attribute__((ext_vector_type(4))) float f32x4;
typedef __attribute__((ext_vector_type(8))) __bf16 bf16x8;
typedef __attribute__((ext_vector_type(8))) unsigned short u16x8;

__device__ __forceinline__ unsigned short f2bf(float f) {
    unsigned u = __builtin_bit_cast(unsigned, f);
    u += 0x7fffu + ((u >> 16) & 1u);   // round-to-nearest-even
    return (unsigned short)(u >> 16);
}

struct RPtrs { const float* R[NB]; };

// ---- pack u0/i0 into transposed bf16 [DD][NN] (B-operand layout) ----
__global__ __launch_bounds__(256)
void pack_kernel(const float* ue, const float* ie,
                 unsigned short* Y1T, unsigned short* X1T) {
    __shared__ __attribute__((aligned(16))) unsigned short Tl[DD][LDK];
    const float* S = blockIdx.y ? ie : ue;
    unsigned short* Dst = blockIdx.y ? X1T : Y1T;
    int n0 = blockIdx.x * 64;
    int t = threadIdx.x, r = t >> 2, q = t & 3;
    const float* sp = S + (size_t)(n0 + r) * DD + q * 16;
#pragma unroll
    for (int c = 0; c < 4; ++c) {
        f32x4 v = *(const f32x4*)(sp + c * 4);
#pragma unroll
        for (int j = 0; j < 4; ++j) Tl[q * 16 + c * 4 + j][r] = f2bf(v[j]);
    }
    __syncthreads();
    int d = t >> 2, seg = t & 3;
    *(u16x8*)(Dst + (size_t)d * NN + n0 + seg * 16)     = *(const u16x8*)&Tl[d][seg * 16];
    *(u16x8*)(Dst + (size_t)d * NN + n0 + seg * 16 + 8) = *(const u16x8*)&Tl[d][seg * 16 + 8];
}

// ---- main GEMM: mode 0 -> U = R @ X (+rowsum), mode 1 -> I = R^T @ Y (+colsum) ----
__global__ __launch_bounds__(256)
void gemm_pass(RPtrs rp, const unsigned short* Xt, long xstride,
               const unsigned short* Yt, long ystride,
               float* U, float* I, float* rs, float* cs, int do_deg) {
    __shared__ __attribute__((aligned(16))) unsigned short Al[BM][LDK];
    __shared__ __attribute__((aligned(16))) unsigned short Bl[DD][LDK];
    __shared__ float csred[4][4][16];

    const int b = blockIdx.y;
    const int mode = blockIdx.z;
    const int m0 = blockIdx.x * BM;
    const float* R = rp.R[b];
    const unsigned short* Bsrc = mode ? (Yt + (size_t)b * ystride)
                                      : (Xt + (size_t)b * xstride);
    const int t = threadIdx.x;
    const int r = t >> 2, q = t & 3;        // staging decomposition
    const int w = t >> 6, l = t & 63;       // wave id / lane
    const int lg = l >> 4, lm = l & 15;

    f32x4 acc[4] = {f32x4{0,0,0,0}, f32x4{0,0,0,0}, f32x4{0,0,0,0}, f32x4{0,0,0,0}};
    float rsum = 0.f;
    float csum[16];
#pragma unroll
    for (int i = 0; i < 16; ++i) csum[i] = 0.f;

    for (int k0 = 0; k0 < NN; k0 += BK) {
        if (mode == 0) {
            // A tile natural: Al[m][k] <- R[m0+r][k0 + q*16 + 0..15]
            const float* src = R + (size_t)(m0 + r) * NN + k0 + q * 16;
#pragma unroll
            for (int c = 0; c < 2; ++c) {
                f32x4 v0 = *(const f32x4*)(src + c * 8);
                f32x4 v1 = *(const f32x4*)(src + c * 8 + 4);
                u16x8 h;
#pragma unroll
                for (int j = 0; j < 4; ++j) {
                    h[j]     = f2bf(v0[j]);
                    h[4 + j] = f2bf(v1[j]);
                    if (do_deg) rsum += v0[j] + v1[j];
                }
                *(u16x8*)&Al[r][q * 16 + c * 8] = h;
            }
        } else {
            // A tile transposed: Al[j][i] <- R[k0+r][m0 + q*16 + w]
            const float* src = R + (size_t)(k0 + r) * NN + m0 + q * 16;
#pragma unroll
            for (int c = 0; c < 4; ++c) {
                f32x4 v = *(const f32x4*)(src + c * 4);
#pragma unroll
                for (int j = 0; j < 4; ++j) {
                    Al[q * 16 + c * 4 + j][r] = f2bf(v[j]);
                    if (do_deg) csum[c * 4 + j] += v[j];
                }
            }
        }
        // B tile: Bl[d][k] <- Bsrc[d][k0 + ...]  (already transposed bf16 in global)
        {
            const unsigned short* bs = Bsrc + (size_t)r * NN + k0 + q * 16;
            *(u16x8*)&Bl[r][q * 16]     = *(const u16x8*)bs;
            *(u16x8*)&Bl[r][q * 16 + 8] = *(const u16x8*)(bs + 8);
        }
        __syncthreads();
#pragma unroll
        for (int ks = 0; ks < 2; ++ks) {
            bf16x8 a = *(const bf16x8*)&Al[w * 16 + lm][ks * 32 + lg * 8];
#pragma unroll
            for (int dt = 0; dt < 4; ++dt) {
                bf16x8 bb = *(const bf16x8*)&Bl[dt * 16 + lm][ks * 32 + lg * 8];
                acc[dt] = __builtin_amdgcn_mfma_f32_16x16x32_bf16(a, bb, acc[dt], 0, 0, 0);
            }
        }
        __syncthreads();
    }

    if (do_deg) {
        if (mode == 0) {
            rsum += __shfl_xor(rsum, 1);
            rsum += __shfl_xor(rsum, 2);
            if (q == 0) rs[(size_t)b * NN + m0 + r] = rsum;
        } else {
#pragma unroll
            for (int i = 0; i < 16; ++i) {
                csum[i] += __shfl_xor(csum[i], 4);
                csum[i] += __shfl_xor(csum[i], 8);
                csum[i] += __shfl_xor(csum[i], 16);
                csum[i] += __shfl_xor(csum[i], 32);
            }
            if (l < 4) {
#pragma unroll
                for (int i = 0; i < 16; ++i) csred[w][l][i] = csum[i];
            }
            __syncthreads();
            if (t < 64) {
                float s = csred[0][t >> 4][t & 15] + csred[1][t >> 4][t & 15]
                        + csred[2][t >> 4][t & 15] + csred[3][t >> 4][t & 15];
                cs[(size_t)b * NN + m0 + t] = s;
            }
        }
    }

    float* Out = (mode == 0 ? U : I) + (size_t)b * NN * DD;
#pragma unroll
    for (int dt = 0; dt < 4; ++dt)
#pragma unroll
        for (int j = 0; j < 4; ++j)
            Out[(size_t)(m0 + w * 16 + lg * 4 + j) * DD + dt * 16 + lm] = acc[dt][j];
}

// ---- between passes: u1 = U1/(rs+eps), i1 = I1/(cs+eps), store transposed bf16 ----
__global__ __launch_bounds__(256)
void mid_kernel(const float* U1, const float* I1, const float* rs, const float* cs,
                unsigned short* Y2T, unsigned short* X2T) {
    __shared__ __attribute__((aligned(16))) unsigned short Tl[DD][LDK];
    int b = blockIdx.y, z = blockIdx.z;
    int n0 = blockIdx.x * 64;
    const float* S = (z ? I1 : U1) + ((size_t)b * NN + n0) * DD;
    const float* dg = (z ? cs : rs) + (size_t)b * NN + n0;
    unsigned short* Dst = (z ? X2T : Y2T) + (size_t)b * DD * NN;
    int t = threadIdx.x, r = t >> 2, q = t & 3;
    float inv = 1.f / (dg[r] + EPSV);
#pragma unroll
    for (int c = 0; c < 4; ++c) {
        f32x4 v = *(const f32x4*)(S + r * DD + q * 16 + c * 4);
#pragma unroll
        for (int j = 0; j < 4; ++j) Tl[q * 16 + c * 4 + j][r] = f2bf(v[j] * inv);
    }
    __syncthreads();
    int d = t >> 2, seg = t & 3;
    *(u16x8*)(Dst + (size_t)d * NN + n0 + seg * 16)     = *(const u16x8*)&Tl[d][seg * 16];
    *(u16x8*)(Dst + (size_t)d * NN + n0 + seg * 16 + 8) = *(const u16x8*)&Tl[d][seg * 16 + 8];
}

// ---- combine into [14][NN][DD] output ----
__global__ __launch_bounds__(256)
void epilogue_kernel(const float* U1, const float* U2, const float* I1, const float* I2,
                     const float* rs, const float* cs,
                     const float* addc, const float* addf, const float* addk,
                     float* out) {
    size_t idx = (size_t)blockIdx.x * 256 + threadIdx.x;
    const size_t ND = (size_t)NN * DD;
    if (idx >= 14 * ND) return;
    int s = (int)(idx / ND);
    size_t rem = idx % ND;
    int n = (int)(rem / DD);
    float val;
    if (s < 4) {
        size_t o = (size_t)s * ND + rem;
        val = (U1[o] + U2[o]) * 0.5f / (rs[(size_t)s * NN + n] + EPSV);
    } else if (s < 8) {
        int b = s - 4;
        size_t o = (size_t)b * ND + rem;
        val = (I1[o] + I2[o]) * 0.5f / (cs[(size_t)b * NN + n] + EPSV);
    } else if (s < 11) {
        int b = 4 + (s - 8);
        size_t o = (size_t)b * ND + rem;
        const float* ad = (s == 8) ? addc : (s == 9) ? addf : addk;
        val = (U1[o] + U2[o]) * 0.5f / (rs[(size_t)b * NN + n] + EPSV) + ad[rem];
    } else {
        int b = 4 + (s - 11);
        size_t o = (size_t)b * ND + rem;
        val = (I1[o] + I2[o]) * 0.5f / (cs[(size_t)b * NN + n] + EPSV);
    }
    out[idx] = val;
}

extern "C" void kernel_launch(void* const* d_in, const int* in_sizes, int n_in,
                              void* d_out, int out_size, void* d_ws, size_t ws_size,
                              hipStream_t stream) {
    const float* ue = (const float*)d_in[0];
    const float* ie = (const float*)d_in[1];
    RPtrs rp;
    for (int i = 0; i < NB; ++i) rp.R[i] = (const float*)d_in[2 + i];
    const float* addc = (const float*)d_in[9];
    const float* addf = (const float*)d_in[10];
    const float* addk = (const float*)d_in[11];
    float* out = (float*)d_out;

    char* ws = (char*)d_ws;
    size_t off = 0;
    auto alloc = [&](size_t bytes) -> void* {
        void* p = ws + off;
        off += (bytes + 255) & ~(size_t)255;
        return p;
    };
    unsigned short* X1T = (unsigned short*)alloc((size_t)DD * NN * 2);
    unsigned short* Y1T = (unsigned short*)alloc((size_t)DD * NN * 2);
    unsigned short* X2T = (unsigned short*)alloc((size_t)NB * DD * NN * 2);
    unsigned short* Y2T = (unsigned short*)alloc((size_t)NB * DD * NN * 2);
    float* U1 = (float*)alloc((size_t)NB * NN * DD * 4);
    float* I1 = (float*)alloc((size_t)NB * NN * DD * 4);
    float* U2 = (float*)alloc((size_t)NB * NN * DD * 4);
    float* I2 = (float*)alloc((size_t)NB * NN * DD * 4);
    float* rs = (float*)alloc((size_t)NB * NN * 4);
    float* cs = (float*)alloc((size_t)NB * NN * 4);

    pack_kernel<<<dim3(NN / 64, 2, 1), 256, 0, stream>>>(ue, ie, Y1T, X1T);
    gemm_pass<<<dim3(NN / BM, NB, 2), 256, 0, stream>>>(rp, X1T, 0, Y1T, 0,
                                                        U1, I1, rs, cs, 1);
    mid_kernel<<<dim3(NN / 64, NB, 2), 256, 0, stream>>>(U1, I1, rs, cs, Y2T, X2T);
    gemm_pass<<<dim3(NN / BM, NB, 2), 256, 0, stream>>>(rp, X2T, (long)DD * NN,
                                                        Y2T, (long)DD * NN,
                                                        U2, I2, rs, cs, 0);
    epilogue_kernel<<<dim3((14 * NN * DD + 255) / 256, 1, 1), 256, 0, stream>>>(
        U1, U2, I1, I2, rs, cs, addc, addf, addk, out);
}

// Round 2
// 399.157 us; speedup vs baseline: 1.0684x; 1.0684x over previous
//
#include <hip/hip_runtime.h>

#define NN 4096
#define DD 64
#define NB 7
#define EPSV 1e-8f
#define NT 64          // K tiles of 64
#define LDK 72

typedef __attribute__((ext_vector_type(4))) float f32x4;
typedef __attribute__((ext_vector_type(8))) __bf16 bf16x8;
typedef __attribute__((ext_vector_type(8))) unsigned short u16x8;

__device__ __forceinline__ unsigned short f2bf(float f) {
    unsigned u = __builtin_bit_cast(unsigned, f);
    u += 0x7fffu + ((u >> 16) & 1u);
    return (unsigned short)(u >> 16);
}

struct RPtrs { const float* R[NB]; };

__device__ __forceinline__ void gl_lds16(const void* g, void* l) {
    __builtin_amdgcn_global_load_lds(
        (const __attribute__((address_space(1))) unsigned*)g,
        (__attribute__((address_space(3))) unsigned*)l, 16, 0, 0);
}

// ---- pack u0/i0 into transposed bf16 [DD][NN] ----
__global__ __launch_bounds__(256)
void pack_kernel(const float* ue, const float* ie,
                 unsigned short* Y1T, unsigned short* X1T) {
    __shared__ __attribute__((aligned(16))) unsigned short Tl[DD][LDK];
    const float* S = blockIdx.y ? ie : ue;
    unsigned short* Dst = blockIdx.y ? X1T : Y1T;
    int n0 = blockIdx.x * 64;
    int t = threadIdx.x, r = t >> 2, q = t & 3;
    const float* sp = S + (size_t)(n0 + r) * DD + q * 16;
#pragma unroll
    for (int c = 0; c < 4; ++c) {
        f32x4 v = *(const f32x4*)(sp + c * 4);
#pragma unroll
        for (int j = 0; j < 4; ++j) Tl[q * 16 + c * 4 + j][r] = f2bf(v[j]);
    }
    __syncthreads();
    int d = t >> 2, seg = t & 3;
    *(u16x8*)(Dst + (size_t)d * NN + n0 + seg * 16)     = *(const u16x8*)&Tl[d][seg * 16];
    *(u16x8*)(Dst + (size_t)d * NN + n0 + seg * 16 + 8) = *(const u16x8*)&Tl[d][seg * 16 + 8];
}

// ---- main GEMM: mode 0 -> U = R @ X (+rowsum), mode 1 -> I = R^T @ Y (+colsum) ----
// A staged as raw f32 via global_load_lds with swizzled source chunks;
// B staged as bf16 via global_load_lds with swizzled source chunks.
// 2-phase double-buffered pipeline, counted vmcnt(6).
__global__ __launch_bounds__(256)
void gemm_pass(RPtrs rp, const unsigned short* Xt, long xstride,
               const unsigned short* Yt, long ystride,
               float* U, float* I, float* rs, float* cs, int do_deg, int rev) {
    __shared__ __attribute__((aligned(16))) float As[2][64 * 64];   // 32 KB
    __shared__ __attribute__((aligned(16))) __bf16 Bs[2][64 * 64];  // 16 KB

    const int by = rev ? (NB - 1 - (int)blockIdx.y) : (int)blockIdx.y;
    const int mode = blockIdx.z;
    const int m0 = blockIdx.x * 64;
    const float* Rg = rp.R[by];
    const unsigned short* Bsrc = mode ? (Yt + (size_t)by * ystride)
                                      : (Xt + (size_t)by * xstride);
    const int t = threadIdx.x;
    const int w = t >> 6, l = t & 63;
    const int lg = l >> 4, lm = l & 15;

    // ---- staging address precompute ----
    const float* agp[4]; unsigned aoff[4];
    const unsigned short* bgp[2]; unsigned boff[2];
#pragma unroll
    for (int i = 0; i < 4; ++i) {
        int r = w * 16 + i * 4 + (l >> 4);   // local row staged by this lane
        int s = l & 15;                       // LDS 16B slot within row
        int dr = (r & 7) + 2 * ((r >> 3) & 3);
        int c = (s & 8) | ((s - dr) & 7);     // global 16B chunk (inverse swizzle)
        if (mode == 0) agp[i] = Rg + (size_t)(m0 + r) * NN + c * 4;
        else           agp[i] = Rg + (size_t)r * NN + m0 + c * 4;
        aoff[i] = (unsigned)(w * 16 + i * 4) * 256;
    }
#pragma unroll
    for (int j = 0; j < 2; ++j) {
        int d = w * 16 + j * 8 + (l >> 3);
        int s = l & 7;
        int c = (s - (d & 7)) & 7;
        bgp[j] = Bsrc + (size_t)d * NN + c * 8;
        boff[j] = (unsigned)(w * 16 + j * 8) * 128;
    }
    const size_t astep = mode ? (size_t)64 * NN : (size_t)64;  // f32 elems / tile

    // ---- fragment-read slot precompute ----
    const int r0 = w * 16 + lm;                       // mode-0 row
    const int drr = (r0 & 7) + 2 * ((r0 >> 3) & 3);
    int sA[2][2];
#pragma unroll
    for (int ks = 0; ks < 2; ++ks)
#pragma unroll
        for (int dl = 0; dl < 2; ++dl) {
            int c = ks * 8 + lg * 2 + dl;
            sA[ks][dl] = (c & 8) | ((c + drr) & 7);
        }
    const int n = w * 16 + lm, cn = n >> 2, nbb = n & 3;  // mode-1 column
    int sB[2];
#pragma unroll
    for (int ks = 0; ks < 2; ++ks) sB[ks] = ((ks * 4 + lg) + (lm & 7)) & 7;

    f32x4 acc[4] = {f32x4{0,0,0,0}, f32x4{0,0,0,0}, f32x4{0,0,0,0}, f32x4{0,0,0,0}};
    float dsum = 0.f;

    auto STAGE = [&](int tt, int pb) {
#pragma unroll
        for (int i = 0; i < 4; ++i)
            gl_lds16(agp[i] + (size_t)tt * astep, (char*)(&As[pb][0]) + aoff[i]);
#pragma unroll
        for (int j = 0; j < 2; ++j)
            gl_lds16(bgp[j] + (size_t)tt * 64, (char*)(&Bs[pb][0]) + boff[j]);
    };

    STAGE(0, 0);
    for (int tt = 0; tt < NT; ++tt) {
        const int pb = tt & 1;
        if (tt + 1 < NT) {
            STAGE(tt + 1, pb ^ 1);
            asm volatile("s_waitcnt vmcnt(6)" ::: "memory");
        } else {
            asm volatile("s_waitcnt vmcnt(0)" ::: "memory");
        }
        __builtin_amdgcn_s_barrier();

        const float* Ab = &As[pb][0];
        const __bf16* Bb = &Bs[pb][0];
#pragma unroll
        for (int ks = 0; ks < 2; ++ks) {
            bf16x8 af;
            if (mode == 0) {
                f32x4 a0 = *(const f32x4*)(Ab + r0 * 64 + sA[ks][0] * 4);
                f32x4 a1 = *(const f32x4*)(Ab + r0 * 64 + sA[ks][1] * 4);
#pragma unroll
                for (int e = 0; e < 4; ++e) {
                    af[e]     = (__bf16)a0[e];
                    af[4 + e] = (__bf16)a1[e];
                }
                if (do_deg)
                    dsum += a0[0] + a0[1] + a0[2] + a0[3] + a1[0] + a1[1] + a1[2] + a1[3];
            } else {
#pragma unroll
                for (int j = 0; j < 8; ++j) {
                    int k = ks * 32 + lg * 8 + j;
                    int slot = (cn & 8) | ((cn + j + 2 * lg) & 7);
                    float v = Ab[k * 64 + slot * 4 + nbb];
                    af[j] = (__bf16)v;
                    if (do_deg) dsum += v;
                }
            }
#pragma unroll
            for (int dt = 0; dt < 4; ++dt) {
                bf16x8 bb = *(const bf16x8*)(Bb + (dt * 16 + lm) * 64 + sB[ks] * 8);
                acc[dt] = __builtin_amdgcn_mfma_f32_16x16x32_bf16(af, bb, acc[dt], 0, 0, 0);
            }
        }
        __builtin_amdgcn_s_barrier();
    }

    if (do_deg) {
        dsum += __shfl_xor(dsum, 16);
        dsum += __shfl_xor(dsum, 32);
        if (lg == 0) {
            float* dst = mode ? cs : rs;
            dst[(size_t)by * NN + m0 + w * 16 + lm] = dsum;
        }
    }

    float* Out = (mode == 0 ? U : I) + (size_t)by * NN * DD;
#pragma unroll
    for (int dt = 0; dt < 4; ++dt)
#pragma unroll
        for (int j = 0; j < 4; ++j)
            Out[(size_t)(m0 + w * 16 + lg * 4 + j) * DD + dt * 16 + lm] = acc[dt][j];
}

// ---- between passes: u1 = U1/(rs+eps), i1 = I1/(cs+eps), store transposed bf16 ----
__global__ __launch_bounds__(256)
void mid_kernel(const float* U1, const float* I1, const float* rs, const float* cs,
                unsigned short* Y2T, unsigned short* X2T) {
    __shared__ __attribute__((aligned(16))) unsigned short Tl[DD][LDK];
    int b = blockIdx.y, z = blockIdx.z;
    int n0 = blockIdx.x * 64;
    const float* S = (z ? I1 : U1) + ((size_t)b * NN + n0) * DD;
    const float* dg = (z ? cs : rs) + (size_t)b * NN + n0;
    unsigned short* Dst = (z ? X2T : Y2T) + (size_t)b * DD * NN;
    int t = threadIdx.x, r = t >> 2, q = t & 3;
    float inv = 1.f / (dg[r] + EPSV);
#pragma unroll
    for (int c = 0; c < 4; ++c) {
        f32x4 v = *(const f32x4*)(S + r * DD + q * 16 + c * 4);
#pragma unroll
        for (int j = 0; j < 4; ++j) Tl[q * 16 + c * 4 + j][r] = f2bf(v[j] * inv);
    }
    __syncthreads();
    int d = t >> 2, seg = t & 3;
    *(u16x8*)(Dst + (size_t)d * NN + n0 + seg * 16)     = *(const u16x8*)&Tl[d][seg * 16];
    *(u16x8*)(Dst + (size_t)d * NN + n0 + seg * 16 + 8) = *(const u16x8*)&Tl[d][seg * 16 + 8];
}

// ---- combine into [14][NN][DD] output (vectorized f32x4) ----
__global__ __launch_bounds__(256)
void epilogue_kernel(const float* U1, const float* U2, const float* I1, const float* I2,
                     const float* rs, const float* cs,
                     const float* addc, const float* addf, const float* addk,
                     float* out) {
    size_t idx4 = (size_t)blockIdx.x * 256 + threadIdx.x;
    const size_t ND4 = (size_t)NN * DD / 4;
    if (idx4 >= 14 * ND4) return;
    int s = (int)(idx4 / ND4);
    size_t rem4 = idx4 % ND4;
    int nrow = (int)(rem4 / (DD / 4));
    size_t rem = rem4 * 4;
    f32x4 val;
    if (s < 4) {
        size_t o = (size_t)s * NN * DD + rem;
        f32x4 a = *(const f32x4*)(U1 + o), b = *(const f32x4*)(U2 + o);
        float sc = 0.5f / (rs[(size_t)s * NN + nrow] + EPSV);
        val = (a + b) * sc;
    } else if (s < 8) {
        int bb = s - 4;
        size_t o = (size_t)bb * NN * DD + rem;
        f32x4 a = *(const f32x4*)(I1 + o), b = *(const f32x4*)(I2 + o);
        float sc = 0.5f / (cs[(size_t)bb * NN + nrow] + EPSV);
        val = (a + b) * sc;
    } else if (s < 11) {
        int bb = 4 + (s - 8);
        size_t o = (size_t)bb * NN * DD + rem;
        const float* ad = (s == 8) ? addc : (s == 9) ? addf : addk;
        f32x4 a = *(const f32x4*)(U1 + o), b = *(const f32x4*)(U2 + o);
        f32x4 c = *(const f32x4*)(ad + rem);
        float sc = 0.5f / (rs[(size_t)bb * NN + nrow] + EPSV);
        val = (a + b) * sc + c;
    } else {
        int bb = 4 + (s - 11);
        size_t o = (size_t)bb * NN * DD + rem;
        f32x4 a = *(const f32x4*)(I1 + o), b = *(const f32x4*)(I2 + o);
        float sc = 0.5f / (cs[(size_t)bb * NN + nrow] + EPSV);
        val = (a + b) * sc;
    }
    *(f32x4*)(out + idx4 * 4) = val;
}

extern "C" void kernel_launch(void* const* d_in, const int* in_sizes, int n_in,
                              void* d_out, int out_size, void* d_ws, size_t ws_size,
                              hipStream_t stream) {
    const float* ue = (const float*)d_in[0];
    const float* ie = (const float*)d_in[1];
    RPtrs rp;
    for (int i = 0; i < NB; ++i) rp.R[i] = (const float*)d_in[2 + i];
    const float* addc = (const float*)d_in[9];
    const float* addf = (const float*)d_in[10];
    const float* addk = (const float*)d_in[11];
    float* out = (float*)d_out;

    char* ws = (char*)d_ws;
    size_t off = 0;
    auto alloc = [&](size_t bytes) -> void* {
        void* p = ws + off;
        off += (bytes + 255) & ~(size_t)255;
        return p;
    };
    unsigned short* X1T = (unsigned short*)alloc((size_t)DD * NN * 2);
    unsigned short* Y1T = (unsigned short*)alloc((size_t)DD * NN * 2);
    unsigned short* X2T = (unsigned short*)alloc((size_t)NB * DD * NN * 2);
    unsigned short* Y2T = (unsigned short*)alloc((size_t)NB * DD * NN * 2);
    float* U1 = (float*)alloc((size_t)NB * NN * DD * 4);
    float* I1 = (float*)alloc((size_t)NB * NN * DD * 4);
    float* U2 = (float*)alloc((size_t)NB * NN * DD * 4);
    float* I2 = (float*)alloc((size_t)NB * NN * DD * 4);
    float* rs = (float*)alloc((size_t)NB * NN * 4);
    float* cs = (float*)alloc((size_t)NB * NN * 4);

    pack_kernel<<<dim3(NN / 64, 2, 1), 256, 0, stream>>>(ue, ie, Y1T, X1T);
    gemm_pass<<<dim3(NN / 64, NB, 2), 256, 0, stream>>>(rp, X1T, 0, Y1T, 0,
                                                        U1, I1, rs, cs, 1, 0);
    mid_kernel<<<dim3(NN / 64, NB, 2), 256, 0, stream>>>(U1, I1, rs, cs, Y2T, X2T);
    gemm_pass<<<dim3(NN / 64, NB, 2), 256, 0, stream>>>(rp, X2T, (long)DD * NN,
                                                        Y2T, (long)DD * NN,
                                                        U2, I2, rs, cs, 0, 1);
    epilogue_kernel<<<dim3((14 * NN * DD / 4 + 255) / 256, 1, 1), 256, 0, stream>>>(
        U1, U2, I1, I2, rs, cs, addc, addf, addk, out);
}